// Round 8
// baseline (541.472 us; speedup 1.0000x reference)
//
#include <hip/hip_runtime.h>

// BinaryLSTMCell v7 for MI355X (gfx950).
// B=65536, D=256, U=256. out = [h_new | h_new | c_new], f32.
//
// v2-v6 invariant diagnosed: per-step W-frag loads from L2/L3 expose 600-900cy
// latency every 512-cy step (A-stream evicts W from L2). v7 restructures:
//  - prep_a: pre-build A as MFMA fragments (f16 hi/lo) in d_ws (128MB).
//  - GEMM: wave=(side,gate), W half-resident in regs (reload 2x/chunk after
//    last use), A frags ping-pong prefetched, ZERO barriers/LDS in k-loop,
//    16 waves/CU (launch_bounds(512,4)), persistent blocks with XCD-aware
//    chunk schedule so co-timed blocks share A chunks in L2.
//  - epilogue per 64-row chunk: lgkm-only barriers, 8-wave LDS gate-combine.

#define NB 65536

typedef _Float16 f16x8 __attribute__((ext_vector_type(8)));
typedef __fp16 fp16x2 __attribute__((ext_vector_type(2)));
typedef float f32x16 __attribute__((ext_vector_type(16)));

__device__ __forceinline__ float htanh(float x) {
  return __builtin_amdgcn_fmed3f(x, -1.0f, 1.0f);
}

// ---------------------------------------------------------------------------
// prep_w: binarize weights into 1024 MFMA B-fragments (1KB each).
// fragid = ((k16*2 + side)*8 + u32)*4 + gate;
//   lane l: n = gate*256 + u32*32 + (l&31), k = k16*16 + (l>>5)*8 + e.
// ---------------------------------------------------------------------------
__global__ void prep_w(const float* __restrict__ Kf, const float* __restrict__ RKf,
                       unsigned short* __restrict__ wfrag) {
  __shared__ unsigned short sgn[32][72];
  const int b = blockIdx.x;            // 256 blocks
  const int side = b >> 7, kt = (b >> 4) & 7, nt = b & 15;
  const float* M = side ? RKf : Kf;
  const int t = threadIdx.x;
  {
    const int k = t >> 3, n8 = (t & 7) << 3;
    const float* p = M + (kt * 32 + k) * 1024 + nt * 64 + n8;
    float4 v0 = *(const float4*)p;
    float4 v1 = *(const float4*)(p + 4);
    float xs[8] = {v0.x, v0.y, v0.z, v0.w, v1.x, v1.y, v1.z, v1.w};
#pragma unroll
    for (int i = 0; i < 8; ++i)
      sgn[k][n8 + i] = (xs[i] >= 0.f) ? 0x3C00u : 0xBC00u;
  }
  __syncthreads();
  const int fl = t >> 6, l = t & 63;
  const int j = fl >> 1, uhh = fl & 1;
  const int nloc = uhh * 32 + (l & 31);
  const int kloc = j * 16 + (l >> 5) * 8;
  unsigned short o[8];
#pragma unroll
  for (int e = 0; e < 8; ++e) o[e] = sgn[kloc + e][nloc];
  const int ng = nt * 64 + nloc;
  const int gate = ng >> 8, u32 = (ng >> 5) & 7;
  const int k16 = kt * 2 + j;
  const int fragid = ((k16 * 2 + side) * 8 + u32) * 4 + gate;
  uint4 ov;
  ov.x = (unsigned)o[0] | ((unsigned)o[1] << 16);
  ov.y = (unsigned)o[2] | ((unsigned)o[3] << 16);
  ov.z = (unsigned)o[4] | ((unsigned)o[5] << 16);
  ov.w = (unsigned)o[6] | ((unsigned)o[7] << 16);
  *(uint4*)((char*)wfrag + fragid * 1024 + l * 16) = ov;
}

// ---------------------------------------------------------------------------
// prep_a: build A-fragment images (f16 hi/lo split; htanh applied to h side).
// fragidx(strip, k16, side, term) = ((strip*16 + k16)*2 + side)*2 + term.
// Frag: lane l holds 16B: row = strip*32 + (l&31), k = k16*16 + (l>>5)*8 + e.
// Grid: strip(2048) x kq(4) x side(2) = 16384 blocks, 256 thr.
// ---------------------------------------------------------------------------
__global__ __launch_bounds__(256)
void prep_a(const float* __restrict__ xin, const float* __restrict__ hin,
            char* __restrict__ aimg) {
  __shared__ float tile[32][68];
  const int b = blockIdx.x;
  const int side = b & 1, kq = (b >> 1) & 3, strip = b >> 3;
  const float* src = side ? hin : xin;
  const int t = threadIdx.x;
  {
    const int row = t >> 3, kc = (t & 7) << 3;
    const float* p = src + (strip * 32 + row) * 256 + kq * 64 + kc;
    float4 v0 = *(const float4*)p;
    float4 v1 = *(const float4*)(p + 4);
    *(float4*)&tile[row][kc] = v0;
    *(float4*)&tile[row][kc + 4] = v1;
  }
  __syncthreads();
  const int w = t >> 6, l = t & 63;
  const int l31 = l & 31, lh = l >> 5;
  const int k16 = kq * 4 + w;
  const int c0 = w * 16 + lh * 8;
  float4 u0 = *(const float4*)&tile[l31][c0];
  float4 u1 = *(const float4*)&tile[l31][c0 + 4];
  float v0 = u0.x, v1 = u0.y, v2 = u0.z, v3 = u0.w;
  float v4 = u1.x, v5 = u1.y, v6 = u1.z, v7 = u1.w;
  if (side) {
    v0 = htanh(v0); v1 = htanh(v1); v2 = htanh(v2); v3 = htanh(v3);
    v4 = htanh(v4); v5 = htanh(v5); v6 = htanh(v6); v7 = htanh(v7);
  }
  fp16x2 h01 = __builtin_amdgcn_cvt_pkrtz(v0, v1);
  fp16x2 h23 = __builtin_amdgcn_cvt_pkrtz(v2, v3);
  fp16x2 h45 = __builtin_amdgcn_cvt_pkrtz(v4, v5);
  fp16x2 h67 = __builtin_amdgcn_cvt_pkrtz(v6, v7);
  fp16x2 l01 = __builtin_amdgcn_cvt_pkrtz(v0 - (float)h01[0], v1 - (float)h01[1]);
  fp16x2 l23 = __builtin_amdgcn_cvt_pkrtz(v2 - (float)h23[0], v3 - (float)h23[1]);
  fp16x2 l45 = __builtin_amdgcn_cvt_pkrtz(v4 - (float)h45[0], v5 - (float)h45[1]);
  fp16x2 l67 = __builtin_amdgcn_cvt_pkrtz(v6 - (float)h67[0], v7 - (float)h67[1]);
  uint4 H, L;
  H.x = __builtin_bit_cast(unsigned, h01); H.y = __builtin_bit_cast(unsigned, h23);
  H.z = __builtin_bit_cast(unsigned, h45); H.w = __builtin_bit_cast(unsigned, h67);
  L.x = __builtin_bit_cast(unsigned, l01); L.y = __builtin_bit_cast(unsigned, l23);
  L.z = __builtin_bit_cast(unsigned, l45); L.w = __builtin_bit_cast(unsigned, l67);
  char* dst = aimg + (size_t)(((strip * 16 + k16) * 2 + side) * 2) * 1024 + l * 16;
  *(uint4*)dst = H;
  *(uint4*)(dst + 1024) = L;
}

// ---------------------------------------------------------------------------
// GEMM: persistent 1024 blocks x 512 thr (8 waves = gate*2 + side).
// Block: u32 = U fixed; loops 8 chunks of 64 rows (2 strips).
// Per wave per chunk: 64 MFMA (2 strips x 16 k16 x hi/lo), acc = 2 x f32x16.
// ---------------------------------------------------------------------------
__global__ __launch_bounds__(512, 4)
void blstm_gemm(const char* __restrict__ aimg, const unsigned short* __restrict__ wfrag,
                const float* __restrict__ cin, float* __restrict__ out) {
  __shared__ char ex[65536];           // 8 waves x 2 strips x 4KB

  const int bid = blockIdx.x;          // 1024
  const int xcd = bid & 7, j = bid >> 3;
  const int U = j & 7, g8 = j >> 3;    // g8: 0..15
  const int tid = threadIdx.x, lane = tid & 63, w = tid >> 6;
  const int s = w & 1, gate = w >> 1;
  const int l31 = lane & 31, lh = lane >> 5;

  // W base: fragid = ((k16*2+s)*8+U)*4+gate -> byte k16*65536 + s*32768 + U*4096 + gate*1024
  const char* wb = (const char*)wfrag + s * 32768 + U * 4096 + gate * 1024 + lane * 16;
  // A frag byte: (chunk*2+st)*65536 + k16*4096 + s*2048 + term*1024 + lane*16
  const char* ab0 = aimg + s * 2048 + lane * 16;

  const int chunk0 = xcd * 128 + g8 * 8;

  f16x8 wreg[8];
  f32x16 acc[2];
  f16x8 a0h, a0l, a1h, a1l, b0h, b0l, b1h, b1l;

#define AADDR(C, ST, K, T) (ab0 + (size_t)((C) * 2 + (ST)) * 65536 + (K) * 4096 + (T) * 1024)

  // prologue: W lo-half + A(chunk0, k0)
#pragma unroll
  for (int k = 0; k < 8; ++k) wreg[k] = *(const f16x8*)(wb + k * 65536);
  a0h = *(const f16x8*)AADDR(chunk0, 0, 0, 0);
  a0l = *(const f16x8*)AADDR(chunk0, 0, 0, 1);
  a1h = *(const f16x8*)AADDR(chunk0, 1, 0, 0);
  a1l = *(const f16x8*)AADDR(chunk0, 1, 0, 1);

#define MFMA_STEP(CH0, CL0, CH1, CL1, WF) do {                                \
    acc[0] = __builtin_amdgcn_mfma_f32_32x32x16_f16(CH0, WF, acc[0], 0, 0, 0); \
    acc[0] = __builtin_amdgcn_mfma_f32_32x32x16_f16(CL0, WF, acc[0], 0, 0, 0); \
    acc[1] = __builtin_amdgcn_mfma_f32_32x32x16_f16(CH1, WF, acc[1], 0, 0, 0); \
    acc[1] = __builtin_amdgcn_mfma_f32_32x32x16_f16(CL1, WF, acc[1], 0, 0, 0); \
  } while (0)

// K step: prefetch A(K+1) into NXT regs (or next chunk's k0 at K==15),
// 4 MFMA on CUR, W half-reload after last use of that half.
#define KS(K, C0H, C0L, C1H, C1L, N0H, N0L, N1H, N1L) do {                    \
    if ((K) < 15) {                                                           \
      N0H = *(const f16x8*)AADDR(chunk, 0, (K) + 1, 0);                       \
      N0L = *(const f16x8*)AADDR(chunk, 0, (K) + 1, 1);                       \
      N1H = *(const f16x8*)AADDR(chunk, 1, (K) + 1, 0);                       \
      N1L = *(const f16x8*)AADDR(chunk, 1, (K) + 1, 1);                       \
    } else if (t < 7) {                                                       \
      N0H = *(const f16x8*)AADDR(chunk + 1, 0, 0, 0);                         \
      N0L = *(const f16x8*)AADDR(chunk + 1, 0, 0, 1);                         \
      N1H = *(const f16x8*)AADDR(chunk + 1, 1, 0, 0);                         \
      N1L = *(const f16x8*)AADDR(chunk + 1, 1, 0, 1);                         \
    }                                                                         \
    MFMA_STEP(C0H, C0L, C1H, C1L, wreg[(K) & 7]);                             \
    if ((K) == 7) {                                                           \
      _Pragma("unroll")                                                       \
      for (int kk = 0; kk < 8; ++kk)                                          \
        wreg[kk] = *(const f16x8*)(wb + (8 + kk) * 65536);                    \
    }                                                                         \
    if ((K) == 15 && t < 7) {                                                 \
      _Pragma("unroll")                                                       \
      for (int kk = 0; kk < 8; ++kk)                                          \
        wreg[kk] = *(const f16x8*)(wb + kk * 65536);                          \
    }                                                                         \
  } while (0)

#pragma unroll 1
  for (int t = 0; t < 8; ++t) {
    const int chunk = chunk0 + t;
    const int m0 = chunk * 64;
    const f32x16 zacc = {};
    acc[0] = zacc;
    acc[1] = zacc;

    KS(0,  a0h, a0l, a1h, a1l,  b0h, b0l, b1h, b1l);
    KS(1,  b0h, b0l, b1h, b1l,  a0h, a0l, a1h, a1l);
    KS(2,  a0h, a0l, a1h, a1l,  b0h, b0l, b1h, b1l);
    KS(3,  b0h, b0l, b1h, b1l,  a0h, a0l, a1h, a1l);
    KS(4,  a0h, a0l, a1h, a1l,  b0h, b0l, b1h, b1l);
    KS(5,  b0h, b0l, b1h, b1l,  a0h, a0l, a1h, a1l);
    KS(6,  a0h, a0l, a1h, a1l,  b0h, b0l, b1h, b1l);
    KS(7,  b0h, b0l, b1h, b1l,  a0h, a0l, a1h, a1l);
    KS(8,  a0h, a0l, a1h, a1l,  b0h, b0l, b1h, b1l);
    KS(9,  b0h, b0l, b1h, b1l,  a0h, a0l, a1h, a1l);
    KS(10, a0h, a0l, a1h, a1l,  b0h, b0l, b1h, b1l);
    KS(11, b0h, b0l, b1h, b1l,  a0h, a0l, a1h, a1l);
    KS(12, a0h, a0l, a1h, a1l,  b0h, b0l, b1h, b1l);
    KS(13, b0h, b0l, b1h, b1l,  a0h, a0l, a1h, a1l);
    KS(14, a0h, a0l, a1h, a1l,  b0h, b0l, b1h, b1l);
    KS(15, b0h, b0l, b1h, b1l,  a0h, a0l, a1h, a1l);

    // ---- epilogue: issue cin early, 2 lgkm-only barriers, 8-wave combine ----
    const int Rb = w * 8 + lh * 4;     // this wave combines rows Rb..Rb+3, col l31
    float ct0 = cin[(m0 + Rb + 0) * 256 + U * 32 + l31];
    float ct1 = cin[(m0 + Rb + 1) * 256 + U * 32 + l31];
    float ct2 = cin[(m0 + Rb + 2) * 256 + U * 32 + l31];
    float ct3 = cin[(m0 + Rb + 3) * 256 + U * 32 + l31];

    asm volatile("s_waitcnt lgkmcnt(0)\n\ts_barrier" ::: "memory");  // barA
#pragma unroll
    for (int st = 0; st < 2; ++st)
#pragma unroll
      for (int q = 0; q < 4; ++q) {
        float4 v;
        v.x = acc[st][q * 4 + 0]; v.y = acc[st][q * 4 + 1];
        v.z = acc[st][q * 4 + 2]; v.w = acc[st][q * 4 + 3];
        *(float4*)(ex + w * 8192 + st * 4096 + q * 1024 + lane * 16) = v;
      }
    asm volatile("s_waitcnt lgkmcnt(0)\n\ts_barrier" ::: "memory");  // barB

    float cts[4] = {ct0, ct1, ct2, ct3};
#pragma unroll
    for (int i = 0; i < 4; ++i) {
      const int R = Rb + i;
      const int st = R >> 5, r32 = R & 31;
      const int q = r32 >> 3, el = r32 & 3;
      const int sl = l31 + ((r32 >> 2) & 1) * 32;
      const int off = st * 4096 + q * 1024 + sl * 16 + el * 4;
      // region w_src = gate*2 + side: 0:x_i 1:r_i 2:x_f 3:r_f 4:x_c 5:r_c 6:x_o 7:r_o
      const float xi = htanh(*(const float*)(ex + 0 * 8192 + off));
      const float ri =        *(const float*)(ex + 1 * 8192 + off);
      const float xf = htanh(*(const float*)(ex + 2 * 8192 + off));
      const float rf =        *(const float*)(ex + 3 * 8192 + off);
      const float xc = htanh(*(const float*)(ex + 4 * 8192 + off));
      const float rc =        *(const float*)(ex + 5 * 8192 + off);
      const float xo = htanh(*(const float*)(ex + 6 * 8192 + off));
      const float ro =        *(const float*)(ex + 7 * 8192 + off);
      // reference gate crossing: f = ht(x_i + r_f), i = ht(x_f + r_i)
      const float fg   = htanh(xi + rf);
      const float ig   = htanh(xf + ri);
      const float cand = htanh(xc + rc);
      const float og   = htanh(xo + ro);
      const float c0 = htanh(cts[i]);
      const float cn = fg * c0 + ig * cand;
      const float hn = htanh(og * htanh(cn));
      const int o1 = (m0 + R) * 256 + U * 32 + l31;
      out[o1] = hn;
      out[16777216 + o1] = hn;
      out[33554432 + o1] = cn;
    }
  }
#undef KS
#undef MFMA_STEP
#undef AADDR
}

extern "C" void kernel_launch(void* const* d_in, const int* in_sizes, int n_in,
                              void* d_out, int out_size, void* d_ws, size_t ws_size,
                              hipStream_t stream) {
  const float* xin = (const float*)d_in[0];
  const float* hin = (const float*)d_in[1];
  const float* cin = (const float*)d_in[2];
  const float* kf  = (const float*)d_in[3];
  const float* rkf = (const float*)d_in[4];
  float* out = (float*)d_out;

  unsigned short* wfrag = (unsigned short*)d_ws;        // 1MB
  char* aimg = (char*)d_ws + (1 << 20);                 // 128MB frag image

  prep_w<<<256, 256, 0, stream>>>(kf, rkf, wfrag);
  prep_a<<<16384, 256, 0, stream>>>(xin, hin, aimg);
  blstm_gemm<<<1024, 512, 0, stream>>>(aimg, wfrag, cin, out);
}

// Round 9
// 522.441 us; speedup vs baseline: 1.0364x; 1.0364x over previous
//
#include <hip/hip_runtime.h>

// BinaryLSTMCell v8 for MI355X (gfx950).
// B=65536, D=256, U=256. out = [h_new | h_new | c_new], f32.
//
// Law from v2-v7: MfmaUtil == operand-bytes-per-MFMA vs memory-tier budget.
// v8 maximizes reuse: wave = 4 n-frags (gate-pair x both sides) x 2 m-strips,
// acc 128 regs; A from LDS at 512B/MFMA; W ping-pong resident in regs
// (reload 1 step ahead from L2 at 256B/MFMA, latency hidden by full step).
// Gate-pairing {i,f}/{c,o} makes the LSTM combine nearly wave-local: epilogue
// exchanges only (f,i) through LDS. 256thr/4wave blocks, 64KB LDS, 2 blk/CU.

#define NB 65536

typedef _Float16 f16x8 __attribute__((ext_vector_type(8)));
typedef __fp16 fp16x2 __attribute__((ext_vector_type(2)));
typedef float f32x16 __attribute__((ext_vector_type(16)));

__device__ __forceinline__ float htanh(float x) {
  return __builtin_amdgcn_fmed3f(x, -1.0f, 1.0f);
}

__device__ __forceinline__ unsigned pk2(float a, float b) {
  fp16x2 p = __builtin_amdgcn_cvt_pkrtz(a, b);
  return __builtin_bit_cast(unsigned, p);
}

// ---------------------------------------------------------------------------
// prep_w: binarize weights into 1024 MFMA B-fragments (1KB each). v7-proven.
// fragid = ((k16*2 + side)*8 + u32)*4 + gate;
//   lane l: n = gate*256 + u32*32 + (l&31), k = k16*16 + (l>>5)*8 + e.
// ---------------------------------------------------------------------------
__global__ void prep_w(const float* __restrict__ Kf, const float* __restrict__ RKf,
                       unsigned short* __restrict__ wfrag) {
  __shared__ unsigned short sgn[32][72];
  const int b = blockIdx.x;            // 256 blocks
  const int side = b >> 7, kt = (b >> 4) & 7, nt = b & 15;
  const float* M = side ? RKf : Kf;
  const int t = threadIdx.x;
  {
    const int k = t >> 3, n8 = (t & 7) << 3;
    const float* p = M + (kt * 32 + k) * 1024 + nt * 64 + n8;
    float4 v0 = *(const float4*)p;
    float4 v1 = *(const float4*)(p + 4);
    float xs[8] = {v0.x, v0.y, v0.z, v0.w, v1.x, v1.y, v1.z, v1.w};
#pragma unroll
    for (int i = 0; i < 8; ++i)
      sgn[k][n8 + i] = (xs[i] >= 0.f) ? 0x3C00u : 0xBC00u;
  }
  __syncthreads();
  const int fl = t >> 6, l = t & 63;
  const int j = fl >> 1, uhh = fl & 1;
  const int nloc = uhh * 32 + (l & 31);
  const int kloc = j * 16 + (l >> 5) * 8;
  unsigned short o[8];
#pragma unroll
  for (int e = 0; e < 8; ++e) o[e] = sgn[kloc + e][nloc];
  const int ng = nt * 64 + nloc;
  const int gate = ng >> 8, u32 = (ng >> 5) & 7;
  const int k16 = kt * 2 + j;
  const int fragid = ((k16 * 2 + side) * 8 + u32) * 4 + gate;
  uint4 ov;
  ov.x = (unsigned)o[0] | ((unsigned)o[1] << 16);
  ov.y = (unsigned)o[2] | ((unsigned)o[3] << 16);
  ov.z = (unsigned)o[4] | ((unsigned)o[5] << 16);
  ov.w = (unsigned)o[6] | ((unsigned)o[7] << 16);
  *(uint4*)((char*)wfrag + fragid * 1024 + l * 16) = ov;
}

// ---------------------------------------------------------------------------
// GEMM+combine. Grid 2048 x 256 thr (4 waves), persistent over 2 m-chunks.
// Wave w: gp = w>>1 (gate pair {2gp, 2gp+1}), uhf = w&1 (u32 = U*2+uhf).
// Wave nf = side*2 + gx: acc[st][nf], st = m-strip (BM=64 = 2 strips).
// K loop: 8 steps of 32k; A staged f32->f16 hi/lo in LDS dbuf; W in regs
// (wA/wB ping-pong, next pair loaded from L2 each step).
// ---------------------------------------------------------------------------
__global__ __launch_bounds__(256, 2)
void blstm_gemm(const float* __restrict__ xin, const float* __restrict__ hin,
                const float* __restrict__ cin, const unsigned short* __restrict__ wfrag,
                float* __restrict__ out) {
  __shared__ char smem[65536];   // [0,32K): A staging dbuf; [32K,64K): (f,i) ex

  const int bid = blockIdx.x;
  const int swz = (bid & 7) * 256 + (bid >> 3);  // XCD swizzle (2048%8==0)
  const int U = swz & 3;                          // 64-u block
  const int mg = swz >> 2;                        // 0..511

  const int tid = threadIdx.x, lane = tid & 63, w = tid >> 6;
  const int gp = w >> 1, uhf = w & 1;
  const int l31 = lane & 31, lh = lane >> 5;

  // ---- staging role: 128 thr/side, thread = (side, row, k16-half) ----
  const int sSide = tid >> 7;
  const int sRow = (tid & 127) >> 1;             // 0..63
  const int sKh = tid & 1;                       // which k16 of the 32k step
  const float* const aP0 = (sSide ? hin : xin) + (size_t)sRow * 256 + sKh * 16;
  // staging write: frag fid = ((sKh*2+side)*2+strip)*2 + term
  char* const swr = smem +
      ((((sKh * 2 + sSide) * 2 + (sRow >> 5)) * 2) * 1024) + (sRow & 31) * 16;

  // ---- W addressing: byte = k16*65536 + (side*32 + u32*4 + gate)*1024 ----
  const char* const wq = (const char*)wfrag + lane * 16;
  int wbOff[4];
#pragma unroll
  for (int nf = 0; nf < 4; ++nf) {
    const int side = nf >> 1, gate = gp * 2 + (nf & 1);
    wbOff[nf] = (side * 32 + (U * 2 + uhf) * 4 + gate) * 1024;
  }

  f32x16 acc[2][4];
  f16x8 wA[8], wB[8];        // [k16loc*4 + nf]
  float4 av0, av1, av2, av3;

  // ---- initial W pair 0 ----
#pragma unroll
  for (int j = 0; j < 2; ++j)
#pragma unroll
    for (int nf = 0; nf < 4; ++nf)
      wA[j * 4 + nf] = *(const f16x8*)(wq + (0 + j) * 65536 + wbOff[nf]);

#define CVT_STORE(B) do {                                                    \
    float e_[16] = {av0.x, av0.y, av0.z, av0.w, av1.x, av1.y, av1.z, av1.w,  \
                    av2.x, av2.y, av2.z, av2.w, av3.x, av3.y, av3.z, av3.w}; \
    if (sSide) {                                                             \
      _Pragma("unroll") for (int i_ = 0; i_ < 16; ++i_) e_[i_] = htanh(e_[i_]); \
    }                                                                        \
    unsigned hw_[8], lw_[8];                                                 \
    _Pragma("unroll")                                                        \
    for (int i_ = 0; i_ < 8; ++i_) {                                         \
      fp16x2 h_ = __builtin_amdgcn_cvt_pkrtz(e_[2 * i_], e_[2 * i_ + 1]);    \
      hw_[i_] = __builtin_bit_cast(unsigned, h_);                            \
      lw_[i_] = pk2(e_[2 * i_] - (float)h_[0], e_[2 * i_ + 1] - (float)h_[1]); \
    }                                                                        \
    char* wp_ = swr + (B) * 16384;                                           \
    *(uint4*)(wp_)        = make_uint4(hw_[0], hw_[1], hw_[2], hw_[3]);      \
    *(uint4*)(wp_ + 512)  = make_uint4(hw_[4], hw_[5], hw_[6], hw_[7]);      \
    *(uint4*)(wp_ + 1024) = make_uint4(lw_[0], lw_[1], lw_[2], lw_[3]);      \
    *(uint4*)(wp_ + 1536) = make_uint4(lw_[4], lw_[5], lw_[6], lw_[7]);      \
  } while (0)

#define K16(J, WARR, RB) do {                                                \
    _Pragma("unroll")                                                        \
    for (int sd_ = 0; sd_ < 2; ++sd_) {                                      \
      _Pragma("unroll")                                                      \
      for (int st_ = 0; st_ < 2; ++st_) {                                    \
        f16x8 ah_ = *(const f16x8*)((RB) + (J) * 8192 + sd_ * 4096 + st_ * 2048); \
        f16x8 al_ = *(const f16x8*)((RB) + (J) * 8192 + sd_ * 4096 + st_ * 2048 + 1024); \
        acc[st_][sd_ * 2 + 0] = __builtin_amdgcn_mfma_f32_32x32x16_f16(      \
            ah_, WARR[(J) * 4 + sd_ * 2 + 0], acc[st_][sd_ * 2 + 0], 0, 0, 0); \
        acc[st_][sd_ * 2 + 1] = __builtin_amdgcn_mfma_f32_32x32x16_f16(      \
            ah_, WARR[(J) * 4 + sd_ * 2 + 1], acc[st_][sd_ * 2 + 1], 0, 0, 0); \
        acc[st_][sd_ * 2 + 0] = __builtin_amdgcn_mfma_f32_32x32x16_f16(      \
            al_, WARR[(J) * 4 + sd_ * 2 + 0], acc[st_][sd_ * 2 + 0], 0, 0, 0); \
        acc[st_][sd_ * 2 + 1] = __builtin_amdgcn_mfma_f32_32x32x16_f16(      \
            al_, WARR[(J) * 4 + sd_ * 2 + 1], acc[st_][sd_ * 2 + 1], 0, 0, 0); \
      }                                                                      \
    }                                                                        \
  } while (0)

#define STEP(S, WCUR, WNXT, LAST) do {                                       \
    asm volatile("s_waitcnt lgkmcnt(0)\n\ts_barrier" ::: "memory");          \
    if (!(LAST)) {                                                           \
      av0 = *(const float4*)(aPc + ((S) + 1) * 32);                          \
      av1 = *(const float4*)(aPc + ((S) + 1) * 32 + 4);                      \
      av2 = *(const float4*)(aPc + ((S) + 1) * 32 + 8);                      \
      av3 = *(const float4*)(aPc + ((S) + 1) * 32 + 12);                     \
    }                                                                        \
    _Pragma("unroll")                                                        \
    for (int j_ = 0; j_ < 2; ++j_)                                           \
      _Pragma("unroll")                                                      \
      for (int nf_ = 0; nf_ < 4; ++nf_)                                      \
        WNXT[j_ * 4 + nf_] = *(const f16x8*)(                                \
            wq + (((((S) + 1) & 7) * 2) + j_) * 65536 + wbOff[nf_]);         \
    {                                                                        \
      const char* rb_ = smem + ((S) & 1) * 16384 + lane * 16;                \
      __builtin_amdgcn_s_setprio(1);                                         \
      K16(0, WCUR, rb_);                                                     \
      K16(1, WCUR, rb_);                                                     \
      __builtin_amdgcn_s_setprio(0);                                         \
    }                                                                        \
    if (!(LAST)) CVT_STORE(((S) + 1) & 1);                                   \
  } while (0)

  float* ex = (float*)(smem + 32768);

#pragma unroll 1
  for (int c = 0; c < 2; ++c) {
    const int m0 = (mg + c * 512) * 64;
    const float* aPc = aP0 + (size_t)m0 * 256;

    // acc reset
    const f32x16 z = {};
#pragma unroll
    for (int st = 0; st < 2; ++st)
#pragma unroll
      for (int nf = 0; nf < 4; ++nf) acc[st][nf] = z;

    // prologue: stage step 0 into buf0
    av0 = *(const float4*)(aPc);
    av1 = *(const float4*)(aPc + 4);
    av2 = *(const float4*)(aPc + 8);
    av3 = *(const float4*)(aPc + 12);
    CVT_STORE(0);

    STEP(0, wA, wB, false);
    STEP(1, wB, wA, false);
    STEP(2, wA, wB, false);
    STEP(3, wB, wA, false);
    STEP(4, wA, wB, false);
    STEP(5, wB, wA, false);
    STEP(6, wA, wB, false);
    STEP(7, wB, wA, true);   // leaves wA = pair0 for next chunk

    // ---- epilogue ----
    // C/D layout: col = lane&31, row(reg r) = (r&3) + 8*(r>>2) + 4*lh
    const int uc = U * 64 + uhf * 32 + l31;
    float cins[32];
    if (gp == 1) {   // prefetch c (in flight during gp0's stores)
#pragma unroll
      for (int st = 0; st < 2; ++st)
#pragma unroll
        for (int q = 0; q < 4; ++q)
#pragma unroll
          for (int i = 0; i < 4; ++i) {
            const int row = st * 32 + 8 * q + 4 * lh + i;
            cins[(st * 4 + q) * 4 + i] = cin[(size_t)(m0 + row) * 256 + uc];
          }
    }
    if (gp == 0) {   // gates {0:i-col, 1:f-col}: compute f,i; store to ex
#pragma unroll
      for (int st = 0; st < 2; ++st)
#pragma unroll
        for (int q = 0; q < 4; ++q) {
          float4 fv, iv;
#pragma unroll
          for (int i = 0; i < 4; ++i) {
            const int r = q * 4 + i;
            // f = ht(ht(x_i) + r_f); i = ht(ht(x_f) + r_i)
            ((float*)&fv)[i] = htanh(htanh(acc[st][0][r]) + acc[st][3][r]);
            ((float*)&iv)[i] = htanh(htanh(acc[st][1][r]) + acc[st][2][r]);
          }
          *(float4*)((char*)ex + (((uhf * 2 + 0) * 2 + st) * 4096) + q * 1024 + lane * 16) = fv;
          *(float4*)((char*)ex + (((uhf * 2 + 1) * 2 + st) * 4096) + q * 1024 + lane * 16) = iv;
        }
    }
    asm volatile("s_waitcnt lgkmcnt(0)\n\ts_barrier" ::: "memory");
    if (gp == 1) {   // gates {2:c-col, 3:o-col}: cand, og; combine + write
#pragma unroll
      for (int st = 0; st < 2; ++st)
#pragma unroll
        for (int q = 0; q < 4; ++q) {
          float4 fv = *(const float4*)((char*)ex + (((uhf * 2 + 0) * 2 + st) * 4096) + q * 1024 + lane * 16);
          float4 iv = *(const float4*)((char*)ex + (((uhf * 2 + 1) * 2 + st) * 4096) + q * 1024 + lane * 16);
#pragma unroll
          for (int i = 0; i < 4; ++i) {
            const int r = q * 4 + i;
            const float cand = htanh(htanh(acc[st][0][r]) + acc[st][2][r]);
            const float og   = htanh(htanh(acc[st][1][r]) + acc[st][3][r]);
            const float fg = ((const float*)&fv)[i];
            const float ig = ((const float*)&iv)[i];
            const float ct = htanh(cins[(st * 4 + q) * 4 + i]);
            const float cn = fg * ct + ig * cand;
            const float hn = htanh(og * htanh(cn));
            const int row = st * 32 + 8 * q + 4 * lh + i;
            const size_t o1 = (size_t)(m0 + row) * 256 + uc;
            out[o1] = hn;
            out[(size_t)NB * 256 + o1] = hn;
            out[2 * (size_t)NB * 256 + o1] = cn;
          }
        }
    }
    // next chunk's STEP(0) barrier re-syncs; ex not touched by staging.
  }
#undef STEP
#undef K16
#undef CVT_STORE
}

extern "C" void kernel_launch(void* const* d_in, const int* in_sizes, int n_in,
                              void* d_out, int out_size, void* d_ws, size_t ws_size,
                              hipStream_t stream) {
  const float* xin = (const float*)d_in[0];
  const float* hin = (const float*)d_in[1];
  const float* cin = (const float*)d_in[2];
  const float* kf  = (const float*)d_in[3];
  const float* rkf = (const float*)d_in[4];
  float* out = (float*)d_out;

  unsigned short* wfrag = (unsigned short*)d_ws;    // 1MB of fragments

  prep_w<<<256, 256, 0, stream>>>(kf, rkf, wfrag);
  blstm_gemm<<<2048, 256, 0, stream>>>(xin, hin, cin, wfrag, out);
}

// Round 11
// 207.397 us; speedup vs baseline: 2.6108x; 2.5190x over previous
//
#include <hip/hip_runtime.h>

// BinaryLSTMCell v9b for MI355X (gfx950) — m201-shaped fused GEMM+LSTM.
// B=65536, D=256, U=256. out = [h_new | h_new | c_new], f32.
//
// Law from v2-v8: MfmaUtil == MFMA-issue / (issue + operand-fetch exposure).
// v9: fat wave tiles (2mf x 2nf x 2side, acc=128), ALL inner-loop operands
// from LDS, K side-phased (x: steps 0-7, h: 8-15), W/A staged 2 steps ahead
// via regs with compiler-counted vmcnt, lgkm-only barriers, in-block LSTM
// gate combine (4-phase padded-LDS exchange).
// v9b: remove all macro token-pasting (PA##0.x pasted 'paB' with pp-number
// '0.x' -> invalid token); registers now passed explicitly.

#define NB 65536

typedef _Float16 f16x8 __attribute__((ext_vector_type(8)));
typedef __fp16 fp16x2 __attribute__((ext_vector_type(2)));
typedef float f32x16 __attribute__((ext_vector_type(16)));

__device__ __forceinline__ float htanh(float x) {
  return __builtin_amdgcn_fmed3f(x, -1.0f, 1.0f);
}

// ---------------------------------------------------------------------------
// prep_w: W step-image [nb 8][s 16][kh 2][gate 4][lane 64][16B]  (1 MB total)
// s: side = s>>3, ks = s&7.  Frag lane l: col = gate*256 + nb*32 + (l&31),
// k = ks*32 + kh*16 + (l>>5)*8 + e.  Value = sign(W) as f16 +-1.
// ---------------------------------------------------------------------------
__global__ __launch_bounds__(512)
void prep_w(const float* __restrict__ Kf, const float* __restrict__ RKf,
            char* __restrict__ wimg) {
  const int b = blockIdx.x;                 // 128 = nb*16 + s
  const int s = b & 15;
  const int side = s >> 3, ks = s & 7;
  const float* M = side ? RKf : Kf;
  const int t = threadIdx.x;                // 512
  const int kh = t >> 8, gate = (t >> 6) & 3, l = t & 63;
  const int nb = b >> 4;
  const int col = gate * 256 + nb * 32 + (l & 31);
  const int k0 = ks * 32 + kh * 16 + (l >> 5) * 8;
  unsigned short o[8];
#pragma unroll
  for (int e = 0; e < 8; ++e)
    o[e] = (M[(k0 + e) * 1024 + col] >= 0.f) ? 0x3C00u : 0xBC00u;
  uint4 ov;
  ov.x = (unsigned)o[0] | ((unsigned)o[1] << 16);
  ov.y = (unsigned)o[2] | ((unsigned)o[3] << 16);
  ov.z = (unsigned)o[4] | ((unsigned)o[5] << 16);
  ov.w = (unsigned)o[6] | ((unsigned)o[7] << 16);
  *(uint4*)(wimg + (size_t)b * 8192 + kh * 4096 + gate * 1024 + l * 16) = ov;
}

// ---------------------------------------------------------------------------
// Main: grid 2048 (256 mb x 8 nb, nb-inner per XCD -> A L2-reuse), 512 thr.
// LDS map: A [buf2][kk4][mf8][slot64][16B] = 64KB at 0
//          B [buf2][kh2][gate4][lane64][16B] = 16KB at 65536
//          EX [sg8][row64][u pad36] f32 = 73728B at 81920 ; total 155648.
// ---------------------------------------------------------------------------
__global__ __launch_bounds__(512, 1)
void blstm_main(const float* __restrict__ xin, const float* __restrict__ hin,
                const float* __restrict__ cin, const char* __restrict__ wimg,
                float* __restrict__ out) {
  extern __shared__ char smem0[];

  const int bid = blockIdx.x;
  const int xcd = bid & 7, ii = bid >> 3;
  const int mb = xcd * 32 + (ii >> 3), nb = ii & 7;
  const int m0 = mb << 8;

  const int tid = threadIdx.x, lane = tid & 63, w = tid >> 6;
  const int mw = w >> 1, nw = w & 1;
  const int l31 = lane & 31, lh = lane >> 5;

  // ---- staging role: thread = (row 0..255, kh 0..1), 16 f32 per step ----
  const int sRow = tid >> 1, sKh = tid & 1;
  const int sMf = sRow >> 5, sL31 = sRow & 31;
  const int sSlot = (sL31 & 24) | ((sL31 ^ sMf) & 7);  // anti-conflict XOR slot
  const float* const xrow = xin + (size_t)(m0 + sRow) * 256 + sKh * 16;
  const float* const hrow = hin + (size_t)(m0 + sRow) * 256 + sKh * 16;
  char* const aWrBase = smem0 + sMf * 1024 + sSlot * 16;   // + buf*32768 + kk*8192 (+512 hi-k)
  const char* const wstep = wimg + (size_t)(nb * 16) * 8192 + tid * 16;

  // ---- compute-side LDS offsets ----
  const int lh512 = lh * 512;
  const int slotA0 = (l31 & 24) | ((l31 ^ (mw * 2 + 0)) & 7);
  const int slotA1 = (l31 & 24) | ((l31 ^ (mw * 2 + 1)) & 7);
  const int aOff0 = (mw * 2 + 0) * 1024 + slotA0 * 16;
  const int aOff1 = (mw * 2 + 1) * 1024 + slotA1 * 16;
  const int bOff0 = (nw * 2 + 0) * 1024 + lane * 16;
  const int bOff1 = (nw * 2 + 1) * 1024 + lane * 16;

  f32x16 acc[2][2][2] = {};   // [side][mfl][nfl]
  uint4 bvA, bvB;
  float4 paA0, paA1, paA2, paA3, paB0, paB1, paB2, paB3;

#define BLOAD(BV, SP) BV = *(const uint4*)(wstep + (size_t)(SP) * 8192)

#define ALOADX(P0, P1, P2, P3, SP) do {                                       \
    const float* p_ = (((SP) >= 8) ? hrow : xrow) + ((SP) & 7) * 32;          \
    P0 = *(const float4*)(p_);      P1 = *(const float4*)(p_ + 4);            \
    P2 = *(const float4*)(p_ + 8);  P3 = *(const float4*)(p_ + 12);           \
  } while (0)

#define BSTORE(BV, SN) \
    *(uint4*)(smem0 + 65536 + ((SN) & 1) * 8192 + tid * 16) = BV

#define ACVT(P0, P1, P2, P3, SN) do {                                         \
    float e_[16] = {(P0).x, (P0).y, (P0).z, (P0).w,                           \
                    (P1).x, (P1).y, (P1).z, (P1).w,                           \
                    (P2).x, (P2).y, (P2).z, (P2).w,                           \
                    (P3).x, (P3).y, (P3).z, (P3).w};                          \
    if ((SN) >= 8) {                                                          \
      _Pragma("unroll") for (int i_ = 0; i_ < 16; ++i_) e_[i_] = htanh(e_[i_]); \
    }                                                                         \
    unsigned hw_[8], lw_[8];                                                  \
    _Pragma("unroll")                                                         \
    for (int i_ = 0; i_ < 8; ++i_) {                                          \
      fp16x2 h_ = __builtin_amdgcn_cvt_pkrtz(e_[2*i_], e_[2*i_+1]);           \
      hw_[i_] = __builtin_bit_cast(unsigned, h_);                             \
      fp16x2 l_ = __builtin_amdgcn_cvt_pkrtz(e_[2*i_]   - (float)h_[0],       \
                                             e_[2*i_+1] - (float)h_[1]);      \
      lw_[i_] = __builtin_bit_cast(unsigned, l_);                             \
    }                                                                         \
    char* b_ = aWrBase + ((SN) & 1) * 32768;                                  \
    *(uint4*)(b_ + sKh * 8192)             = make_uint4(hw_[0], hw_[1], hw_[2], hw_[3]); \
    *(uint4*)(b_ + sKh * 8192 + 512)       = make_uint4(hw_[4], hw_[5], hw_[6], hw_[7]); \
    *(uint4*)(b_ + (2 + sKh) * 8192)       = make_uint4(lw_[0], lw_[1], lw_[2], lw_[3]); \
    *(uint4*)(b_ + (2 + sKh) * 8192 + 512) = make_uint4(lw_[4], lw_[5], lw_[6], lw_[7]); \
  } while (0)

#define MM(AF, BF, AC) AC = __builtin_amdgcn_mfma_f32_32x32x16_f16(AF, BF, AC, 0, 0, 0)

#define COMP(S) do {                                                          \
    const char* a_ = smem0 + ((S) & 1) * 32768 + lh512;                       \
    const char* b_ = smem0 + 65536 + ((S) & 1) * 8192;                        \
    f16x8 B00 = *(const f16x8*)(b_ + bOff0);                                  \
    f16x8 B01 = *(const f16x8*)(b_ + bOff1);                                  \
    f16x8 B10 = *(const f16x8*)(b_ + 4096 + bOff0);                           \
    f16x8 B11 = *(const f16x8*)(b_ + 4096 + bOff1);                           \
    f16x8 A00 = *(const f16x8*)(a_ + 0 * 8192 + aOff0);                       \
    f16x8 A01 = *(const f16x8*)(a_ + 0 * 8192 + aOff1);                       \
    f16x8 A20 = *(const f16x8*)(a_ + 2 * 8192 + aOff0);                       \
    f16x8 A21 = *(const f16x8*)(a_ + 2 * 8192 + aOff1);                       \
    f16x8 A10 = *(const f16x8*)(a_ + 1 * 8192 + aOff0);                       \
    f16x8 A11 = *(const f16x8*)(a_ + 1 * 8192 + aOff1);                       \
    f16x8 A30 = *(const f16x8*)(a_ + 3 * 8192 + aOff0);                       \
    f16x8 A31 = *(const f16x8*)(a_ + 3 * 8192 + aOff1);                       \
    f32x16* ac = &acc[(S) >> 3][0][0];                                        \
    __builtin_amdgcn_s_setprio(1);                                            \
    MM(A00, B00, ac[0]); MM(A00, B01, ac[1]);                                 \
    MM(A01, B00, ac[2]); MM(A01, B01, ac[3]);                                 \
    MM(A20, B00, ac[0]); MM(A20, B01, ac[1]);                                 \
    MM(A21, B00, ac[2]); MM(A21, B01, ac[3]);                                 \
    MM(A10, B10, ac[0]); MM(A10, B11, ac[1]);                                 \
    MM(A11, B10, ac[2]); MM(A11, B11, ac[3]);                                 \
    MM(A30, B10, ac[0]); MM(A30, B11, ac[1]);                                 \
    MM(A31, B10, ac[2]); MM(A31, B11, ac[3]);                                 \
    __builtin_amdgcn_s_setprio(0);                                            \
  } while (0)

// Step S: [loads S+2] [stage S+1 -> LDS] [compute S] [lgkm-only barrier]
#define STEP(S, BVC, C0, C1, C2, C3, BVN, N0, N1, N2, N3) do {                \
    if ((S) < 14) { BLOAD(BVN, (S) + 2); ALOADX(N0, N1, N2, N3, (S) + 2); }   \
    if ((S) < 15) { BSTORE(BVC, (S) + 1); ACVT(C0, C1, C2, C3, (S) + 1); }    \
    COMP(S);                                                                  \
    if ((S) < 15)                                                             \
      asm volatile("s_waitcnt lgkmcnt(0)\n\ts_barrier" ::: "memory");         \
  } while (0)

  // ---- prologue ----
  BLOAD(bvA, 0); ALOADX(paA0, paA1, paA2, paA3, 0);
  BLOAD(bvB, 1); ALOADX(paB0, paB1, paB2, paB3, 1);
  BSTORE(bvA, 0); ACVT(paA0, paA1, paA2, paA3, 0);
  asm volatile("s_waitcnt lgkmcnt(0)\n\ts_barrier" ::: "memory");

  STEP(0,  bvB, paB0, paB1, paB2, paB3, bvA, paA0, paA1, paA2, paA3);
  STEP(1,  bvA, paA0, paA1, paA2, paA3, bvB, paB0, paB1, paB2, paB3);
  STEP(2,  bvB, paB0, paB1, paB2, paB3, bvA, paA0, paA1, paA2, paA3);
  STEP(3,  bvA, paA0, paA1, paA2, paA3, bvB, paB0, paB1, paB2, paB3);
  STEP(4,  bvB, paB0, paB1, paB2, paB3, bvA, paA0, paA1, paA2, paA3);
  STEP(5,  bvA, paA0, paA1, paA2, paA3, bvB, paB0, paB1, paB2, paB3);
  STEP(6,  bvB, paB0, paB1, paB2, paB3, bvA, paA0, paA1, paA2, paA3);
  STEP(7,  bvA, paA0, paA1, paA2, paA3, bvB, paB0, paB1, paB2, paB3);
  STEP(8,  bvB, paB0, paB1, paB2, paB3, bvA, paA0, paA1, paA2, paA3);
  STEP(9,  bvA, paA0, paA1, paA2, paA3, bvB, paB0, paB1, paB2, paB3);
  STEP(10, bvB, paB0, paB1, paB2, paB3, bvA, paA0, paA1, paA2, paA3);
  STEP(11, bvA, paA0, paA1, paA2, paA3, bvB, paB0, paB1, paB2, paB3);
  STEP(12, bvB, paB0, paB1, paB2, paB3, bvA, paA0, paA1, paA2, paA3);
  STEP(13, bvA, paA0, paA1, paA2, paA3, bvB, paB0, paB1, paB2, paB3);
  STEP(14, bvB, paB0, paB1, paB2, paB3, bvA, paA0, paA1, paA2, paA3);
  STEP(15, bvA, paA0, paA1, paA2, paA3, bvB, paB0, paB1, paB2, paB3);

#undef STEP
#undef COMP
#undef MM
#undef ACVT
#undef BSTORE
#undef ALOADX
#undef BLOAD

  // ---- epilogue: 4 row-phases of 64 rows through EX ----
  // C/D layout (verified): col = lane&31, row = (r&3) + 8*(r>>2) + 4*(lane>>5)
  float* const exf = (float*)(smem0 + 81920);   // [sg8][row64][u36] f32
  const int rowl = tid >> 3, u4g = (tid & 7) * 4;

#pragma unroll 1
  for (int p = 0; p < 4; ++p) {
    if (mw == p) {   // waves (p, nw=0/1) dump their 64 rows, all 8 sg between them
#pragma unroll
      for (int side = 0; side < 2; ++side)
#pragma unroll
        for (int mfl = 0; mfl < 2; ++mfl)
#pragma unroll
          for (int nfl = 0; nfl < 2; ++nfl) {
            const int sgW = side * 4 + nw * 2 + nfl;
            float* bp = exf + sgW * 2304 + (mfl * 32 + lh * 4) * 36 + l31;
#pragma unroll
            for (int q = 0; q < 4; ++q)
#pragma unroll
              for (int rl = 0; rl < 4; ++rl)
                bp[(q * 8 + rl) * 36] = acc[side][mfl][nfl][q * 4 + rl];
          }
    }
    const size_t obase = (size_t)(m0 + p * 64 + rowl) * 256 + nb * 32 + u4g;
    float4 cv = *(const float4*)(cin + obase);
    __syncthreads();
    {
      const float* rp = exf + rowl * 36 + u4g;
      float4 v0 = *(const float4*)(rp + 0 * 2304);
      float4 v1 = *(const float4*)(rp + 1 * 2304);
      float4 v2 = *(const float4*)(rp + 2 * 2304);
      float4 v3 = *(const float4*)(rp + 3 * 2304);
      float4 v4 = *(const float4*)(rp + 4 * 2304);
      float4 v5 = *(const float4*)(rp + 5 * 2304);
      float4 v6 = *(const float4*)(rp + 6 * 2304);
      float4 v7 = *(const float4*)(rp + 7 * 2304);
      float4 ho, co;
#pragma unroll
      for (int j = 0; j < 4; ++j) {
        const float xi = htanh(((const float*)&v0)[j]);
        const float xf = htanh(((const float*)&v1)[j]);
        const float xc = htanh(((const float*)&v2)[j]);
        const float xo = htanh(((const float*)&v3)[j]);
        // reference gate crossing: f = ht(x_i + r_f), i = ht(x_f + r_i)
        const float fg   = htanh(xi + ((const float*)&v5)[j]);
        const float ig   = htanh(xf + ((const float*)&v4)[j]);
        const float cand = htanh(xc + ((const float*)&v6)[j]);
        const float og   = htanh(xo + ((const float*)&v7)[j]);
        const float ct = htanh(((const float*)&cv)[j]);
        const float cn = fg * ct + ig * cand;
        const float hn = htanh(og * htanh(cn));
        ((float*)&ho)[j] = hn;
        ((float*)&co)[j] = cn;
      }
      *(float4*)(out + obase) = ho;
      *(float4*)(out + (size_t)NB * 256 + obase) = ho;
      *(float4*)(out + 2 * (size_t)NB * 256 + obase) = co;
    }
    __syncthreads();
  }
}

extern "C" void kernel_launch(void* const* d_in, const int* in_sizes, int n_in,
                              void* d_out, int out_size, void* d_ws, size_t ws_size,
                              hipStream_t stream) {
  const float* xin = (const float*)d_in[0];
  const float* hin = (const float*)d_in[1];
  const float* cin = (const float*)d_in[2];
  const float* kf  = (const float*)d_in[3];
  const float* rkf = (const float*)d_in[4];
  float* out = (float*)d_out;

  char* wimg = (char*)d_ws;      // 1 MB step-image

  (void)hipFuncSetAttribute((const void*)blstm_main,
                            hipFuncAttributeMaxDynamicSharedMemorySize, 155648);

  prep_w<<<128, 512, 0, stream>>>(kf, rkf, wimg);
  blstm_main<<<2048, 512, 155648, stream>>>(xin, hin, cin, wimg, out);
}